// Round 10
// baseline (490.628 us; speedup 1.0000x reference)
//
#include <hip/hip_runtime.h>
#include <cstdint>
#include <cstddef>

// ---------------------------------------------------------------------------
// SIGRegHard: full HIP port of the JAX reference.
// R8: pool GEMM -> bf16-split-3 MFMA; fused centering; gram kernel.
// R9(this): U-space restructure — final U rows are linear combos of UT rows:
//   UF[j]     = sum_{i<=j} W[i][j] * UT[ranked[i]]          (j < 128)
//   UF[128+j] = rnorm_j * (UREXT[j] - sum_i PRJ'[i][j]*UF[i])
//   PRJ' = W^T * (H Rext^T),  rnorm_j = 1/(sqrt(1-||PRJ'_col||^2)+eps).
//   Drops apply_winv / proj_update / rownorm / 192-row final GEMM.
//   + chol_inv: unroll 8 on phase-2c k-loop.
// RNG: JAX threefry partitionable scheme (verified: absmax == 0.0)
// ---------------------------------------------------------------------------

#define THREEFRY_PARTITIONABLE 1

static constexpr int B_ = 2048;   // batch
static constexpr int D_ = 1024;   // feature dim
static constexpr int P_ = 2048;   // pool
static constexpr int HARD_ = 128;
static constexpr int EXTRA_ = 64;
static constexpr int NF_ = 192;   // final direction count
static constexpr int TS_ = 17;    // t steps

typedef short short8v __attribute__((ext_vector_type(8)));
typedef float f32x4v __attribute__((ext_vector_type(4)));

// ------------------------------- RNG ---------------------------------------

__device__ __forceinline__ void threefry2x32(uint32_t k0, uint32_t k1,
                                             uint32_t c0, uint32_t c1,
                                             uint32_t& o0, uint32_t& o1) {
  uint32_t ks0 = k0, ks1 = k1, ks2 = 0x1BD11BDAu ^ k0 ^ k1;
  uint32_t x0 = c0 + ks0;
  uint32_t x1 = c1 + ks1;
#define TF_ROT(r) { x0 += x1; x1 = (x1 << (r)) | (x1 >> (32 - (r))); x1 ^= x0; }
  TF_ROT(13) TF_ROT(15) TF_ROT(26) TF_ROT(6)
  x0 += ks1; x1 += ks2 + 1u;
  TF_ROT(17) TF_ROT(29) TF_ROT(16) TF_ROT(24)
  x0 += ks2; x1 += ks0 + 2u;
  TF_ROT(13) TF_ROT(15) TF_ROT(26) TF_ROT(6)
  x0 += ks0; x1 += ks1 + 3u;
  TF_ROT(17) TF_ROT(29) TF_ROT(16) TF_ROT(24)
  x0 += ks1; x1 += ks2 + 4u;
  TF_ROT(13) TF_ROT(15) TF_ROT(26) TF_ROT(6)
  x0 += ks2; x1 += ks0 + 5u;
#undef TF_ROT
  o0 = x0; o1 = x1;
}

// XLA f32 uniform(-0.99999994, 1) + Giles erfinv (exact XLA coefficients), *sqrt(2)
__device__ __forceinline__ float bits_to_normal(uint32_t bits) {
  uint32_t fb = (bits >> 9) | 0x3f800000u;
  float f = __uint_as_float(fb) - 1.0f;        // [0,1)
  const float lo = -0.99999994f;               // nextafter(-1,0)
  float u = f * 2.0f + lo;
  u = fmaxf(lo, u);
  float w = -log1pf(-u * u);
  float p;
  if (w < 5.0f) {
    w = w - 2.5f;
    p = 2.81022636e-08f;
    p = fmaf(p, w, 3.43273939e-07f);
    p = fmaf(p, w, -3.5233877e-06f);
    p = fmaf(p, w, -4.39150654e-06f);
    p = fmaf(p, w, 0.00021858087f);
    p = fmaf(p, w, -0.00125372503f);
    p = fmaf(p, w, -0.00417768164f);
    p = fmaf(p, w, 0.246640727f);
    p = fmaf(p, w, 1.50140941f);
  } else {
    w = sqrtf(w) - 3.0f;
    p = -0.000200214257f;
    p = fmaf(p, w, 0.000100950558f);
    p = fmaf(p, w, 0.00134934322f);
    p = fmaf(p, w, -0.00367342844f);
    p = fmaf(p, w, 0.00573950773f);
    p = fmaf(p, w, -0.0076224613f);
    p = fmaf(p, w, 0.00943887047f);
    p = fmaf(p, w, 1.00167406f);
    p = fmaf(p, w, 2.83297682f);
  }
  return ((float)1.4142135623730951) * (p * u);
}

__device__ __forceinline__ float tf_normal(uint32_t k0, uint32_t k1,
                                           uint32_t idx) {
  uint32_t a, b;
  threefry2x32(k0, k1, 0u, idx, a, b);   // counter = (hi32(i)=0, lo32(i)=i)
  return bits_to_normal(a ^ b);
}

// ------------------------- small helper kernels ----------------------------

__global__ __launch_bounds__(256) void colsum_part_kernel(const float* __restrict__ Z,
                                                          float* __restrict__ part) {
  int col = blockIdx.x * 256 + threadIdx.x;
  int r0 = blockIdx.y * 64;
  float s = 0.f;
  for (int r = r0; r < r0 + 64; ++r) s += Z[(size_t)r * D_ + col];
  part[blockIdx.y * D_ + col] = s;
}

__global__ __launch_bounds__(256) void colmean_fin_kernel(const float* __restrict__ part,
                                                          float* __restrict__ mean) {
  int col = blockIdx.x * 256 + threadIdx.x;
  float s = 0.f;
  for (int rb = 0; rb < 32; ++rb) s += part[rb * D_ + col];
  mean[col] = s * (1.0f / (float)B_);
}

// gen_pool fused with row normalization: block = pool index p.
__global__ __launch_bounds__(256) void gen_pool_norm_kernel(float* __restrict__ AT,
                                                            const int* __restrict__ seedp) {
  const int p = blockIdx.x;
  const int tid = threadIdx.x;
  uint64_t s = (uint64_t)(int64_t)seedp[0];
  uint32_t k0 = (uint32_t)(s >> 32), k1 = (uint32_t)s;
  float v[4]; float ss = 0.f;
#pragma unroll
  for (int q = 0; q < 4; ++q) {
    int d = tid + 256 * q;
    uint32_t i = (uint32_t)((d << 11) + p);       // d*2048 + p
    v[q] = tf_normal(k0, k1, i);
    ss = fmaf(v[q], v[q], ss);
  }
  __shared__ float red[256];
  red[tid] = ss;
  __syncthreads();
  for (int st = 128; st > 0; st >>= 1) { if (tid < st) red[tid] += red[tid + st]; __syncthreads(); }
  float denom = sqrtf(red[0]) + 1e-12f;
#pragma unroll
  for (int q = 0; q < 4; ++q) {
    int d = tid + 256 * q;
    AT[(size_t)p * D_ + d] = v[q] / denom;
  }
}

// gen_R fused with row normalization: writes AT rows P_ .. P_+63.
__global__ __launch_bounds__(256) void gen_R_norm_kernel(float* __restrict__ AT,
                                                         const int* __restrict__ seedp) {
  const int j = blockIdx.x;
  const int tid = threadIdx.x;
  uint64_t s = (uint64_t)((int64_t)seedp[0] + 9991);
  uint32_t k0 = (uint32_t)(s >> 32), k1 = (uint32_t)s;
  float v[4]; float ss = 0.f;
#pragma unroll
  for (int q = 0; q < 4; ++q) {
    int d = tid + 256 * q;
    uint32_t i = (uint32_t)((d << 6) + j);        // d*64 + j
    v[q] = tf_normal(k0, k1, i);
    ss = fmaf(v[q], v[q], ss);
  }
  __shared__ float red[256];
  red[tid] = ss;
  __syncthreads();
  for (int st = 128; st > 0; st >>= 1) { if (tid < st) red[tid] += red[tid + st]; __syncthreads(); }
  float denom = sqrtf(red[0]) + 1e-12f;
#pragma unroll
  for (int q = 0; q < 4; ++q) {
    int d = tid + 256 * q;
    AT[(size_t)(P_ + j) * D_ + d] = v[q] / denom;
  }
}

// --------------------- MFMA bf16-split-3 GEMM (pool U) ----------------------
__device__ __forceinline__ uint32_t f2bf_rne(float x) {
  uint32_t u = __float_as_uint(x);
  return (u + 0x7fffu + ((u >> 16) & 1u)) >> 16;
}

__global__ __launch_bounds__(512) void gemm_mfma_kernel(const float* __restrict__ A,
                                                        const float* __restrict__ Z,
                                                        const float* __restrict__ meanp,
                                                        float* __restrict__ C) {
  constexpr int BK = 32;
  __shared__ ushort Ah[128][40], Al[128][40], Bh[128][40], Bl[128][40];
  const int tid = threadIdx.x;
  const int lane = tid & 63;
  const int w = tid >> 6;              // wave 0..7
  const int wr = w >> 2;               // 0..1 (64 rows each)
  const int wc = w & 3;                // 0..3 (32 cols each)
  const int m0 = blockIdx.y * 128;
  const int n0 = blockIdx.x * 128;

  f32x4v acc[4][2];
#pragma unroll
  for (int mi = 0; mi < 4; ++mi)
#pragma unroll
    for (int ni = 0; ni < 2; ++ni) acc[mi][ni] = (f32x4v){0.f, 0.f, 0.f, 0.f};

  float4 ra[2], rb[2];
  auto ld = [&](int s) {
    const int k0 = s * BK;
#pragma unroll
    for (int q = 0; q < 2; ++q) {
      int f4 = tid + q * 512;          // 0..1023
      int r = f4 >> 3;                 // 0..127
      int kq = (f4 & 7) * 4;
      ra[q] = *(const float4*)(A + (size_t)(m0 + r) * D_ + k0 + kq);
      float4 z = *(const float4*)(Z + (size_t)(n0 + r) * D_ + k0 + kq);
      float4 mu = *(const float4*)(meanp + k0 + kq);
      rb[q] = make_float4(z.x - mu.x, z.y - mu.y, z.z - mu.z, z.w - mu.w);
    }
  };
  auto st = [&]() {
#pragma unroll
    for (int q = 0; q < 2; ++q) {
      int f4 = tid + q * 512;
      int r = f4 >> 3;
      int kq = (f4 & 7) * 4;
      float av[4] = {ra[q].x, ra[q].y, ra[q].z, ra[q].w};
      float bv[4] = {rb[q].x, rb[q].y, rb[q].z, rb[q].w};
      ushort ah[4], al[4], bh[4], bl[4];
#pragma unroll
      for (int c = 0; c < 4; ++c) {
        uint32_t h = f2bf_rne(av[c]);
        ah[c] = (ushort)h;
        al[c] = (ushort)f2bf_rne(av[c] - __uint_as_float(h << 16));
        uint32_t g = f2bf_rne(bv[c]);
        bh[c] = (ushort)g;
        bl[c] = (ushort)f2bf_rne(bv[c] - __uint_as_float(g << 16));
      }
      *(ushort4*)&Ah[r][kq] = make_ushort4(ah[0], ah[1], ah[2], ah[3]);
      *(ushort4*)&Al[r][kq] = make_ushort4(al[0], al[1], al[2], al[3]);
      *(ushort4*)&Bh[r][kq] = make_ushort4(bh[0], bh[1], bh[2], bh[3]);
      *(ushort4*)&Bl[r][kq] = make_ushort4(bl[0], bl[1], bl[2], bl[3]);
    }
  };
  auto compute = [&]() {
    const int rl = lane & 15;
    const int koff = (lane >> 4) * 8;
    short8v a_h[4], a_l[4], b_h[2], b_l[2];
#pragma unroll
    for (int mi = 0; mi < 4; ++mi) {
      int arow = wr * 64 + mi * 16 + rl;
      a_h[mi] = *(const short8v*)&Ah[arow][koff];
      a_l[mi] = *(const short8v*)&Al[arow][koff];
    }
#pragma unroll
    for (int ni = 0; ni < 2; ++ni) {
      int brow = wc * 32 + ni * 16 + rl;
      b_h[ni] = *(const short8v*)&Bh[brow][koff];
      b_l[ni] = *(const short8v*)&Bl[brow][koff];
    }
#pragma unroll
    for (int mi = 0; mi < 4; ++mi)
#pragma unroll
      for (int ni = 0; ni < 2; ++ni) {
        acc[mi][ni] = __builtin_amdgcn_mfma_f32_16x16x32_bf16(a_h[mi], b_h[ni], acc[mi][ni], 0, 0, 0);
        acc[mi][ni] = __builtin_amdgcn_mfma_f32_16x16x32_bf16(a_h[mi], b_l[ni], acc[mi][ni], 0, 0, 0);
        acc[mi][ni] = __builtin_amdgcn_mfma_f32_16x16x32_bf16(a_l[mi], b_h[ni], acc[mi][ni], 0, 0, 0);
      }
  };

  const int nst = D_ / BK;             // 32
  ld(0);
  for (int s = 0; s < nst; ++s) {
    if (s) __syncthreads();
    st();
    __syncthreads();
    if (s + 1 < nst) ld(s + 1);
    compute();
  }

  const int rl = lane & 15;
  const int rq = (lane >> 4) * 4;
#pragma unroll
  for (int mi = 0; mi < 4; ++mi)
#pragma unroll
    for (int ni = 0; ni < 2; ++ni) {
      int col = n0 + wc * 32 + ni * 16 + rl;
#pragma unroll
      for (int r = 0; r < 4; ++r) {
        int row = m0 + wr * 64 + mi * 16 + rq + r;
        C[(size_t)row * B_ + col] = acc[mi][ni][r];
      }
    }
}

// ------------------------------- vector GEMM --------------------------------
template <int BM, int BN, int BK, int TM, int TN, int NT, bool CENTER_B>
__global__ __launch_bounds__(NT) void gemm_nt_kernel(const float* __restrict__ A,
                                                     const float* __restrict__ Bm,
                                                     const float* __restrict__ meanp,
                                                     float* __restrict__ C,
                                                     int M, int N, int K,
                                                     int lda, int ldb, int ldc) {
  static_assert(TN == 4 || TN == 8, "");
  static_assert((BM * BK) % (4 * NT) == 0, "");
  __shared__ float As[2][BK][BM + 4];
  __shared__ float Bs[2][BK][BN + 4];
  const int tid = threadIdx.x;
  constexpr int TX = BN / TN;
  constexpr int TY = NT / TX;
  static_assert(TY * TM == BM, "");
  const int tx = tid % TX;
  const int ty = tid / TX;
  const int m0 = blockIdx.y * BM;
  const int n0 = blockIdx.x * BN;
  constexpr int NF4 = (BM * BK) / (4 * NT);
  constexpr int F4R = BK / 4;

  float acc[TM][TN];
#pragma unroll
  for (int i = 0; i < TM; ++i)
#pragma unroll
    for (int j = 0; j < TN; ++j) acc[i][j] = 0.f;

  float4 ra[NF4], rb[NF4];

  auto ldnext = [&](int k0) {
#pragma unroll
    for (int q = 0; q < NF4; ++q) {
      int idx = tid + q * NT;
      int r = idx / F4R;
      int kk = (idx % F4R) * 4;
      ra[q] = *(const float4*)(A + (size_t)(m0 + r) * lda + k0 + kk);
      float4 b = *(const float4*)(Bm + (size_t)(n0 + r) * ldb + k0 + kk);
      if constexpr (CENTER_B) {
        float4 mu = *(const float4*)(meanp + k0 + kk);
        b = make_float4(b.x - mu.x, b.y - mu.y, b.z - mu.z, b.w - mu.w);
      }
      rb[q] = b;
    }
  };
  auto stnext = [&](int buf) {
#pragma unroll
    for (int q = 0; q < NF4; ++q) {
      int idx = tid + q * NT;
      int r = idx / F4R;
      int kk = (idx % F4R) * 4;
      As[buf][kk + 0][r] = ra[q].x; As[buf][kk + 1][r] = ra[q].y;
      As[buf][kk + 2][r] = ra[q].z; As[buf][kk + 3][r] = ra[q].w;
      Bs[buf][kk + 0][r] = rb[q].x; Bs[buf][kk + 1][r] = rb[q].y;
      Bs[buf][kk + 2][r] = rb[q].z; Bs[buf][kk + 3][r] = rb[q].w;
    }
  };
  auto compute = [&](int buf) {
#pragma unroll
    for (int kk = 0; kk < BK; ++kk) {
      float a[TM], b[TN];
#pragma unroll
      for (int q = 0; q < TM / 4; ++q) {
        float4 v = *(const float4*)&As[buf][kk][ty * TM + q * 4];
        a[q * 4 + 0] = v.x; a[q * 4 + 1] = v.y; a[q * 4 + 2] = v.z; a[q * 4 + 3] = v.w;
      }
      {
        float4 v = *(const float4*)&Bs[buf][kk][tx * 4];
        b[0] = v.x; b[1] = v.y; b[2] = v.z; b[3] = v.w;
      }
      if constexpr (TN == 8) {
        float4 v = *(const float4*)&Bs[buf][kk][BN / 2 + tx * 4];
        b[4] = v.x; b[5] = v.y; b[6] = v.z; b[7] = v.w;
      }
#pragma unroll
      for (int i = 0; i < TM; ++i)
#pragma unroll
        for (int j = 0; j < TN; ++j) acc[i][j] = fmaf(a[i], b[j], acc[i][j]);
    }
  };

  ldnext(0);
  stnext(0);
  __syncthreads();
  const int nst = K / BK;
  for (int s = 0; s < nst; ++s) {
    const int cur = s & 1;
    if (s + 1 < nst) ldnext((s + 1) * BK);
    compute(cur);
    if (s + 1 < nst) stnext(cur ^ 1);
    __syncthreads();
  }

#pragma unroll
  for (int i = 0; i < TM; ++i) {
    const int gm = m0 + ty * TM + i;
    float4 c0 = make_float4(acc[i][0], acc[i][1], acc[i][2], acc[i][3]);
    *(float4*)(C + (size_t)gm * ldc + n0 + tx * 4) = c0;
    if constexpr (TN == 8) {
      float4 c1 = make_float4(acc[i][4], acc[i][5], acc[i][6], acc[i][7]);
      *(float4*)(C + (size_t)gm * ldc + n0 + BN / 2 + tx * 4) = c1;
    }
  }
}

// ----------------------------- tiled gram ----------------------------------
__global__ __launch_bounds__(256) void gram_kernel(const float* __restrict__ A,
                                                   const float* __restrict__ Bm,
                                                   float* __restrict__ C,
                                                   int K, int ldc) {
  __shared__ float As[32][136];
  __shared__ float BsT[128][36];
  const int tid = threadIdx.x;
  const int i0 = blockIdx.y * 32;
  const int j0 = blockIdx.x * 32;
  const int i = tid >> 3;
  const int jl = (tid & 7) * 4;

  float s[4][4];
#pragma unroll
  for (int m = 0; m < 4; ++m)
#pragma unroll
    for (int c = 0; c < 4; ++c) s[m][c] = 0.f;

  for (int kc = 0; kc < K; kc += 128) {
#pragma unroll
    for (int q = 0; q < 4; ++q) {
      int f4 = tid + 256 * q;
      int r = f4 >> 5;
      int kq = (f4 & 31) * 4;
      float4 va = *(const float4*)(A + (size_t)(i0 + r) * K + kc + kq);
      *(float4*)&As[r][kq] = va;
      float4 vb = *(const float4*)(Bm + (size_t)(j0 + r) * K + kc + kq);
      BsT[kq + 0][r] = vb.x; BsT[kq + 1][r] = vb.y;
      BsT[kq + 2][r] = vb.z; BsT[kq + 3][r] = vb.w;
    }
    __syncthreads();
    for (int k4 = 0; k4 < 128; k4 += 4) {
#pragma unroll
      for (int c = 0; c < 4; ++c) {
        int k = k4 + c;
        float a = As[i][k];
        float4 b = *(const float4*)&BsT[k][jl];
        s[0][c] = fmaf(a, b.x, s[0][c]);
        s[1][c] = fmaf(a, b.y, s[1][c]);
        s[2][c] = fmaf(a, b.z, s[2][c]);
        s[3][c] = fmaf(a, b.w, s[3][c]);
      }
    }
    __syncthreads();
  }
#pragma unroll
  for (int m = 0; m < 4; ++m)
    C[(size_t)(i0 + i) * ldc + j0 + jl + m] = (s[m][0] + s[m][1]) + (s[m][2] + s[m][3]);
}

// --------------------------- ECF + loss ------------------------------------
__global__ __launch_bounds__(256) void ecf_loss_kernel(const float* __restrict__ U,
                                                       float* __restrict__ out_loss) {
  const float* u = U + (size_t)blockIdx.x * B_;
  const int tid = threadIdx.x;
  float sc[TS_], ss[TS_];
#pragma unroll
  for (int k = 0; k < TS_; ++k) { sc[k] = 0.f; ss[k] = 0.f; }

  for (int b = tid; b < B_; b += 256) {
    float x = u[b];
#pragma unroll
    for (int k = 0; k < TS_; ++k) {
      const double tk = -5.0 + 0.625 * (double)k;
      const float trev = (float)(tk * 0.15915494309189535);  // t_k / (2*pi)
      float r = x * trev;
      sc[k] += __builtin_amdgcn_cosf(r);
      ss[k] += __builtin_amdgcn_sinf(r);
    }
  }
#pragma unroll
  for (int k = 0; k < TS_; ++k) {
#pragma unroll
    for (int off = 32; off > 0; off >>= 1) {
      sc[k] += __shfl_down(sc[k], off, 64);
      ss[k] += __shfl_down(ss[k], off, 64);
    }
  }
  __shared__ float rsc[4][TS_], rss[4][TS_];
  int wid = tid >> 6, lane = tid & 63;
  if (lane == 0) {
#pragma unroll
    for (int k = 0; k < TS_; ++k) { rsc[wid][k] = sc[k]; rss[wid][k] = ss[k]; }
  }
  __syncthreads();
  if (tid == 0) {
    float loss = 0.f, prevI = 0.f;
#pragma unroll
    for (int k = 0; k < TS_; ++k) {
      float tk = -5.0f + 0.625f * (float)k;
      float phik = expf(-0.5f * tk * tk);
      float S = (rsc[0][k] + rsc[1][k]) + (rsc[2][k] + rsc[3][k]);
      float T = (rss[0][k] + rss[1][k]) + (rss[2][k] + rss[3][k]);
      float re = S * (1.0f / (float)B_) - phik;
      float im = T * (1.0f / (float)B_);
      float I = (re * re + im * im) * phik;
      if (k > 0) loss += 0.5f * (I + prevI) * 0.625f;
      prevI = I;
    }
    out_loss[blockIdx.x] = loss;
  }
}

// --------------------------- top-k selection -------------------------------
__global__ __launch_bounds__(1024) void sort_kernel(const float* __restrict__ loss,
                                                    int* __restrict__ ranked) {
  __shared__ float ls[P_];
  __shared__ int li[P_];
  int tid = threadIdx.x;
  for (int i = tid; i < P_; i += 1024) { ls[i] = loss[i]; li[i] = i; }
  __syncthreads();
  for (int k = 2; k <= P_; k <<= 1) {
    for (int j = k >> 1; j > 0; j >>= 1) {
      for (int i = tid; i < P_; i += 1024) {
        int ixj = i ^ j;
        if (ixj > i) {
          bool up = ((i & k) == 0);
          float la = ls[i], lb = ls[ixj];
          int ia = li[i], ib = li[ixj];
          bool a_after_b = (la < lb) || (la == lb && ia > ib);
          bool sw = up ? a_after_b : (!a_after_b && !(la == lb && ia == ib));
          if (sw) { ls[i] = lb; ls[ixj] = la; li[i] = ib; li[ixj] = ia; }
        }
      }
      __syncthreads();
    }
  }
  for (int i = tid; i < P_; i += 1024) ranked[i] = li[i];
}

__global__ __launch_bounds__(256) void gather_ht_kernel(const float* __restrict__ AT,
                                                        const int* __restrict__ ranked,
                                                        float* __restrict__ HT) {
  int j = blockIdx.x;
  int src = ranked[j];
  for (int d = threadIdx.x; d < D_; d += 256)
    HT[(size_t)j * D_ + d] = AT[(size_t)src * D_ + d];
}

// ------------------- Cholesky of G + triangular inverse --------------------
__global__ __launch_bounds__(512) void chol_inv_kernel(const float* __restrict__ G,
                                                       float* __restrict__ W) {
  __shared__ float g[HARD_][HARD_ + 1];
  __shared__ float w[HARD_][HARD_ + 1];
  __shared__ float m[16][16 * 7 + 4];
  __shared__ float rinv[HARD_];
  const int tid = threadIdx.x;

  for (int idx = tid; idx < HARD_ * HARD_; idx += 512)
    g[idx >> 7][idx & 127] = G[idx];
  for (int idx = tid; idx < HARD_ * (HARD_ + 1); idx += 512)
    (&w[0][0])[idx] = 0.f;
  __syncthreads();

  const int bcol = tid & 127;
  const int aoff = tid >> 7;
  for (int K = 0; K < 8; ++K) {
    const int b = K << 4;
    const int c0 = b + 16;
    const int nc = HARD_ - c0;

    if (tid < 16) {
      const int j = tid;
      float c[16];
#pragma unroll
      for (int k = 0; k < 16; ++k) c[k] = g[b + k][b + j];
#pragma unroll
      for (int i = 0; i < 16; ++i) {
        float rii = sqrtf(__shfl(c[i], i, 16));
        float rinvi = 1.0f / rii;
        float rij = c[i] * rinvi;
        if (j > i) c[i] = rij;
        if (j == i) c[i] = rii;
#pragma unroll
        for (int a = i + 1; a < 16; ++a) {
          float ria = __shfl(c[i], a, 16);
          if (j >= a) c[a] = fmaf(-ria, rij, c[a]);
        }
      }
#pragma unroll
      for (int k = 0; k < 16; ++k) if (k <= j) g[b + k][b + j] = c[k];
      rinv[b + j] = 1.0f / c[j];
    }
    __syncthreads();

    if (nc > 0) {
      if (tid < nc) {
        const int j = c0 + tid;
        float x[16];
#pragma unroll
        for (int i = 0; i < 16; ++i) {
          float acc = g[b + i][j];
#pragma unroll
          for (int m2 = 0; m2 < i; ++m2)
            acc = fmaf(-g[b + m2][b + i], x[m2], acc);
          x[i] = acc * rinv[b + i];
        }
#pragma unroll
        for (int i = 0; i < 16; ++i) g[b + i][j] = x[i];
      }
      __syncthreads();

      if (bcol >= c0) {
        float rkb[16];
#pragma unroll
        for (int k = 0; k < 16; ++k) rkb[k] = g[b + k][bcol];
        for (int a = c0 + aoff; a <= bcol; a += 4) {
          float acc = g[a][bcol];
#pragma unroll
          for (int k = 0; k < 16; ++k)
            acc = fmaf(-g[b + k][a], rkb[k], acc);
          g[a][bcol] = acc;
        }
      }
    }
    __syncthreads();
  }

  if (tid < HARD_) {
    const int blk = tid >> 4, j = tid & 15, b = blk << 4;
    const float myrinv = rinv[b + j];
    float wcol[16];
#pragma unroll
    for (int i = 15; i >= 0; --i) {
      float s = 0.f;
#pragma unroll
      for (int k = 15; k > i; --k) s = fmaf(g[b + i][b + k], wcol[k], s);
      float v = -rinv[b + i] * s;
      wcol[i] = (i < j) ? v : ((i == j) ? myrinv : 0.f);
    }
#pragma unroll
    for (int k = 0; k < 16; ++k) w[b + k][b + j] = wcol[k];
  }
  __syncthreads();

  for (int I = 6; I >= 0; --I) {
    const int b = I << 4;
    const int c0 = b + 16;
    const int nc = HARD_ - c0;
    const int nel = 16 * nc;
    for (int e = tid; e < nel; e += 512) {
      int r = e / nc, c = e - r * nc;
      float acc = 0.f;
#pragma unroll 8
      for (int k = c0; k < HARD_; ++k)           // trip = multiple of 16
        acc = fmaf(g[b + r][k], w[k][c0 + c], acc);
      m[r][c] = acc;
    }
    __syncthreads();
    for (int e = tid; e < nel; e += 512) {
      int r = e / nc, c = e - r * nc;
      float acc = 0.f;
#pragma unroll
      for (int rp = 0; rp < 16; ++rp)
        acc = fmaf(w[b + r][b + rp], m[rp][c], acc);
      w[b + r][c0 + c] = -acc;
    }
    __syncthreads();
  }

  for (int idx = tid; idx < HARD_ * HARD_; idx += 512)
    W[idx] = w[idx >> 7][idx & 127];
}

// ------------------- U-space epilogue kernels -------------------------------
// PRJ'[i][j] = sum_{k<=i} W[k][i]*GHR[k][j]; RNORM[j] = 1/(sqrt(1-||col||^2)+eps)
__global__ __launch_bounds__(512) void wtrans_kernel(const float* __restrict__ W,
                                                     const float* __restrict__ GHR,
                                                     float* __restrict__ PRJp,
                                                     float* __restrict__ RNORM) {
  __shared__ float wsh[HARD_][HARD_];      // 64 KB
  __shared__ float gsh[HARD_][EXTRA_];     // 32 KB
  __shared__ float psh[HARD_][EXTRA_];     // 32 KB
  const int tid = threadIdx.x;
  for (int e = tid; e < HARD_ * HARD_; e += 512) wsh[e >> 7][e & 127] = W[e];
  for (int e = tid; e < HARD_ * EXTRA_; e += 512) gsh[e >> 6][e & 63] = GHR[e];
  __syncthreads();
  const int j = tid & 63;
  const int ig = tid >> 6;                 // 0..7 (wave-uniform)
#pragma unroll
  for (int q = 0; q < 16; ++q) {
    const int i = ig * 16 + q;
    float acc = 0.f;
    for (int k = 0; k <= i; ++k)
      acc = fmaf(wsh[k][i], gsh[k][j], acc);   // wsh broadcast, gsh 2-way
    psh[i][j] = acc;
    PRJp[i * EXTRA_ + j] = acc;
  }
  __syncthreads();
  if (tid < EXTRA_) {
    float s = 0.f;
    for (int i = 0; i < HARD_; ++i) { float p = psh[i][tid]; s = fmaf(p, p, s); }
    float n = sqrtf(fmaxf(1.f - s, 0.f));
    RNORM[tid] = 1.f / (n + 1e-12f);
  }
}

// UF[j][n] = sum_{i<=j} W[i][j] * UT[ranked[i]][n]   (W lower part is zero)
__global__ __launch_bounds__(256) void uq_kernel(const float* __restrict__ W,
                                                 const float* __restrict__ UT,
                                                 const int* __restrict__ ranked,
                                                 float* __restrict__ UF) {
  __shared__ float wt[HARD_][16];
  __shared__ int rk[HARD_];
  const int tid = threadIdx.x;
  const int j0 = blockIdx.y * 16;
  const int n0 = blockIdx.x * 256;
  for (int e = tid; e < HARD_ * 16; e += 256) {
    int i = e >> 4, jj = e & 15;
    wt[i][jj] = W[i * HARD_ + j0 + jj];
  }
  if (tid < HARD_) rk[tid] = ranked[tid];
  __syncthreads();
  float acc[16];
#pragma unroll
  for (int jj = 0; jj < 16; ++jj) acc[jj] = 0.f;
  const int imax = j0 + 16;                // i > j -> W == 0
  for (int i = 0; i < imax; ++i) {
    float u = UT[(size_t)rk[i] * B_ + n0 + tid];
#pragma unroll
    for (int jj = 0; jj < 16; ++jj) acc[jj] = fmaf(wt[i][jj], u, acc[jj]);
  }
#pragma unroll
  for (int jj = 0; jj < 16; ++jj)
    UF[(size_t)(j0 + jj) * B_ + n0 + tid] = acc[jj];
}

// UF[128+j][n] = RNORM[j] * (UREXT[j][n] - sum_i PRJ'[i][j]*UF[i][n])
__global__ __launch_bounds__(256) void uproj_kernel(const float* __restrict__ PRJp,
                                                    const float* __restrict__ RNORM,
                                                    const float* __restrict__ UREXT,
                                                    float* __restrict__ UF) {
  __shared__ float pc[HARD_][16];
  __shared__ float rn[16];
  const int tid = threadIdx.x;
  const int j0 = blockIdx.y * 16;
  const int n0 = blockIdx.x * 256;
  for (int e = tid; e < HARD_ * 16; e += 256) {
    int i = e >> 4, jj = e & 15;
    pc[i][jj] = PRJp[i * EXTRA_ + j0 + jj];
  }
  if (tid < 16) rn[tid] = RNORM[j0 + tid];
  __syncthreads();
  float acc[16];
#pragma unroll
  for (int jj = 0; jj < 16; ++jj)
    acc[jj] = UREXT[(size_t)(j0 + jj) * B_ + n0 + tid];
  for (int i = 0; i < HARD_; ++i) {
    float u = UF[(size_t)i * B_ + n0 + tid];
#pragma unroll
    for (int jj = 0; jj < 16; ++jj) acc[jj] = fmaf(-pc[i][jj], u, acc[jj]);
  }
#pragma unroll
  for (int jj = 0; jj < 16; ++jj)
    UF[(size_t)(HARD_ + j0 + jj) * B_ + n0 + tid] = acc[jj] * rn[jj];
}

__global__ __launch_bounds__(256) void finalize_kernel(const float* __restrict__ FL,
                                                       float* __restrict__ out) {
  __shared__ float red[256];
  int tid = threadIdx.x;
  red[tid] = (tid < NF_) ? FL[tid] : 0.f;
  __syncthreads();
  for (int s = 128; s > 0; s >>= 1) { if (tid < s) red[tid] += red[tid + s]; __syncthreads(); }
  if (tid == 0) out[0] = (red[0] / (float)NF_) * (float)B_;
}

// ------------------------------- host --------------------------------------

extern "C" void kernel_launch(void* const* d_in, const int* in_sizes, int n_in,
                              void* d_out, int out_size, void* d_ws, size_t ws_size,
                              hipStream_t stream) {
  const float* Z = (const float*)d_in[0];
  const int* seedp = (const int*)d_in[1];
  float* out = (float*)d_out;
  (void)in_sizes; (void)n_in; (void)out_size; (void)ws_size;

  char* ws = (char*)d_ws;
  size_t off = 0;
  auto alloc = [&](size_t bytes) -> char* {
    char* p = ws + off;
    off += (bytes + 255) & ~(size_t)255;
    return p;
  };
  float* AT    = (float*)alloc((size_t)(P_ + EXTRA_) * D_ * 4);  // pool + Rext rows
  float* UT    = (float*)alloc((size_t)P_ * B_ * 4);
  float* LOSS  = (float*)alloc(P_ * 4);
  int*   IDX   = (int*)  alloc(P_ * 4);
  float* HT    = (float*)alloc((size_t)HARD_ * D_ * 4);
  float* G     = (float*)alloc(HARD_ * HARD_ * 4);
  float* W     = (float*)alloc(HARD_ * HARD_ * 4);
  float* GHR   = (float*)alloc(HARD_ * EXTRA_ * 4);
  float* PRJp  = (float*)alloc(HARD_ * EXTRA_ * 4);
  float* RNORM = (float*)alloc(EXTRA_ * 4);
  float* UREXT = (float*)alloc((size_t)EXTRA_ * B_ * 4);
  float* UF    = (float*)alloc((size_t)NF_ * B_ * 4);
  float* FL    = (float*)alloc(NF_ * 4);
  float* PART  = (float*)alloc(32 * D_ * 4);
  float* MEAN  = (float*)alloc(D_ * 4);

  colsum_part_kernel<<<dim3(D_ / 256, 32), 256, 0, stream>>>(Z, PART);
  colmean_fin_kernel<<<D_ / 256, 256, 0, stream>>>(PART, MEAN);

  gen_pool_norm_kernel<<<P_, 256, 0, stream>>>(AT, seedp);
  gen_R_norm_kernel<<<EXTRA_, 256, 0, stream>>>(AT, seedp);

  gemm_mfma_kernel<<<dim3(B_ / 128, P_ / 128), 512, 0, stream>>>(AT, Z, MEAN, UT);
  // UREXT = Rext * zc^T  (64 x 2048)
  gemm_nt_kernel<64, 64, 32, 4, 4, 256, true><<<dim3(B_ / 64, 1), 256, 0, stream>>>(
      AT + (size_t)P_ * D_, Z, MEAN, UREXT, EXTRA_, B_, D_, D_, D_, B_);

  ecf_loss_kernel<<<P_, 256, 0, stream>>>(UT, LOSS);
  sort_kernel<<<1, 1024, 0, stream>>>(LOSS, IDX);
  gather_ht_kernel<<<HARD_, 256, 0, stream>>>(AT, IDX, HT);

  gram_kernel<<<dim3(HARD_ / 32, HARD_ / 32), 256, 0, stream>>>(HT, HT, G, D_, HARD_);
  chol_inv_kernel<<<1, 512, 0, stream>>>(G, W);
  gram_kernel<<<dim3(EXTRA_ / 32, HARD_ / 32), 256, 0, stream>>>(
      HT, AT + (size_t)P_ * D_, GHR, D_, EXTRA_);
  wtrans_kernel<<<1, 512, 0, stream>>>(W, GHR, PRJp, RNORM);

  uq_kernel<<<dim3(B_ / 256, HARD_ / 16), 256, 0, stream>>>(W, UT, IDX, UF);
  uproj_kernel<<<dim3(B_ / 256, EXTRA_ / 16), 256, 0, stream>>>(PRJp, RNORM, UREXT, UF);

  ecf_loss_kernel<<<NF_, 256, 0, stream>>>(UF, FL);
  finalize_kernel<<<1, 256, 0, stream>>>(FL, out);
}

// Round 11
// 408.659 us; speedup vs baseline: 1.2006x; 1.2006x over previous
//
#include <hip/hip_runtime.h>
#include <cstdint>
#include <cstddef>

// ---------------------------------------------------------------------------
// SIGRegHard: full HIP port of the JAX reference.
// R8 (measured 431 us): MFMA pool GEMM + fused centering + gram kernels.
// R9 U-space restructure REVERTED (measured +59 us: replaced wide kernels
//   with 1-32-block latency-bound ones).
// R10(this): chol_inv LDS-vectorization — g/w rows padded to stride 132,
//   m to 116 (16B-aligned rows); phase-2c reads w/m as float4 (ds_read_b128,
//   4 outputs/thread); phase-1d processes column-quads with float4 rkb.
//   Per-element fmaf order unchanged -> bit-identical W.
// RNG: JAX threefry partitionable scheme (verified: absmax == 0.0)
// ---------------------------------------------------------------------------

#define THREEFRY_PARTITIONABLE 1

static constexpr int B_ = 2048;   // batch
static constexpr int D_ = 1024;   // feature dim
static constexpr int P_ = 2048;   // pool
static constexpr int HARD_ = 128;
static constexpr int EXTRA_ = 64;
static constexpr int NF_ = 192;   // final direction count
static constexpr int TS_ = 17;    // t steps

typedef short short8v __attribute__((ext_vector_type(8)));
typedef float f32x4v __attribute__((ext_vector_type(4)));

// ------------------------------- RNG ---------------------------------------

__device__ __forceinline__ void threefry2x32(uint32_t k0, uint32_t k1,
                                             uint32_t c0, uint32_t c1,
                                             uint32_t& o0, uint32_t& o1) {
  uint32_t ks0 = k0, ks1 = k1, ks2 = 0x1BD11BDAu ^ k0 ^ k1;
  uint32_t x0 = c0 + ks0;
  uint32_t x1 = c1 + ks1;
#define TF_ROT(r) { x0 += x1; x1 = (x1 << (r)) | (x1 >> (32 - (r))); x1 ^= x0; }
  TF_ROT(13) TF_ROT(15) TF_ROT(26) TF_ROT(6)
  x0 += ks1; x1 += ks2 + 1u;
  TF_ROT(17) TF_ROT(29) TF_ROT(16) TF_ROT(24)
  x0 += ks2; x1 += ks0 + 2u;
  TF_ROT(13) TF_ROT(15) TF_ROT(26) TF_ROT(6)
  x0 += ks0; x1 += ks1 + 3u;
  TF_ROT(17) TF_ROT(29) TF_ROT(16) TF_ROT(24)
  x0 += ks1; x1 += ks2 + 4u;
  TF_ROT(13) TF_ROT(15) TF_ROT(26) TF_ROT(6)
  x0 += ks2; x1 += ks0 + 5u;
#undef TF_ROT
  o0 = x0; o1 = x1;
}

// XLA f32 uniform(-0.99999994, 1) + Giles erfinv (exact XLA coefficients), *sqrt(2)
__device__ __forceinline__ float bits_to_normal(uint32_t bits) {
  uint32_t fb = (bits >> 9) | 0x3f800000u;
  float f = __uint_as_float(fb) - 1.0f;        // [0,1)
  const float lo = -0.99999994f;               // nextafter(-1,0)
  float u = f * 2.0f + lo;
  u = fmaxf(lo, u);
  float w = -log1pf(-u * u);
  float p;
  if (w < 5.0f) {
    w = w - 2.5f;
    p = 2.81022636e-08f;
    p = fmaf(p, w, 3.43273939e-07f);
    p = fmaf(p, w, -3.5233877e-06f);
    p = fmaf(p, w, -4.39150654e-06f);
    p = fmaf(p, w, 0.00021858087f);
    p = fmaf(p, w, -0.00125372503f);
    p = fmaf(p, w, -0.00417768164f);
    p = fmaf(p, w, 0.246640727f);
    p = fmaf(p, w, 1.50140941f);
  } else {
    w = sqrtf(w) - 3.0f;
    p = -0.000200214257f;
    p = fmaf(p, w, 0.000100950558f);
    p = fmaf(p, w, 0.00134934322f);
    p = fmaf(p, w, -0.00367342844f);
    p = fmaf(p, w, 0.00573950773f);
    p = fmaf(p, w, -0.0076224613f);
    p = fmaf(p, w, 0.00943887047f);
    p = fmaf(p, w, 1.00167406f);
    p = fmaf(p, w, 2.83297682f);
  }
  return ((float)1.4142135623730951) * (p * u);
}

__device__ __forceinline__ float tf_normal(uint32_t k0, uint32_t k1,
                                           uint32_t idx) {
  uint32_t a, b;
  threefry2x32(k0, k1, 0u, idx, a, b);   // counter = (hi32(i)=0, lo32(i)=i)
  return bits_to_normal(a ^ b);
}

// ------------------------- small helper kernels ----------------------------

__global__ __launch_bounds__(256) void colsum_part_kernel(const float* __restrict__ Z,
                                                          float* __restrict__ part) {
  int col = blockIdx.x * 256 + threadIdx.x;
  int r0 = blockIdx.y * 64;
  float s = 0.f;
  for (int r = r0; r < r0 + 64; ++r) s += Z[(size_t)r * D_ + col];
  part[blockIdx.y * D_ + col] = s;
}

__global__ __launch_bounds__(256) void colmean_fin_kernel(const float* __restrict__ part,
                                                          float* __restrict__ mean) {
  int col = blockIdx.x * 256 + threadIdx.x;
  float s = 0.f;
  for (int rb = 0; rb < 32; ++rb) s += part[rb * D_ + col];
  mean[col] = s * (1.0f / (float)B_);
}

// gen_pool fused with row normalization: block = pool index p.
__global__ __launch_bounds__(256) void gen_pool_norm_kernel(float* __restrict__ AT,
                                                            const int* __restrict__ seedp) {
  const int p = blockIdx.x;
  const int tid = threadIdx.x;
  uint64_t s = (uint64_t)(int64_t)seedp[0];
  uint32_t k0 = (uint32_t)(s >> 32), k1 = (uint32_t)s;
  float v[4]; float ss = 0.f;
#pragma unroll
  for (int q = 0; q < 4; ++q) {
    int d = tid + 256 * q;
    uint32_t i = (uint32_t)((d << 11) + p);       // d*2048 + p
    v[q] = tf_normal(k0, k1, i);
    ss = fmaf(v[q], v[q], ss);
  }
  __shared__ float red[256];
  red[tid] = ss;
  __syncthreads();
  for (int st = 128; st > 0; st >>= 1) { if (tid < st) red[tid] += red[tid + st]; __syncthreads(); }
  float denom = sqrtf(red[0]) + 1e-12f;
#pragma unroll
  for (int q = 0; q < 4; ++q) {
    int d = tid + 256 * q;
    AT[(size_t)p * D_ + d] = v[q] / denom;
  }
}

// gen_R fused with row normalization: block = extra index j (writes DIRS rows 128..191).
__global__ __launch_bounds__(256) void gen_R_norm_kernel(float* __restrict__ DIRS,
                                                         const int* __restrict__ seedp) {
  const int j = blockIdx.x;
  const int tid = threadIdx.x;
  uint64_t s = (uint64_t)((int64_t)seedp[0] + 9991);
  uint32_t k0 = (uint32_t)(s >> 32), k1 = (uint32_t)s;
  float v[4]; float ss = 0.f;
#pragma unroll
  for (int q = 0; q < 4; ++q) {
    int d = tid + 256 * q;
    uint32_t i = (uint32_t)((d << 6) + j);        // d*64 + j
    v[q] = tf_normal(k0, k1, i);
    ss = fmaf(v[q], v[q], ss);
  }
  __shared__ float red[256];
  red[tid] = ss;
  __syncthreads();
  for (int st = 128; st > 0; st >>= 1) { if (tid < st) red[tid] += red[tid + st]; __syncthreads(); }
  float denom = sqrtf(red[0]) + 1e-12f;
#pragma unroll
  for (int q = 0; q < 4; ++q) {
    int d = tid + 256 * q;
    DIRS[(size_t)(HARD_ + j) * D_ + d] = v[q] / denom;
  }
}

__global__ __launch_bounds__(256) void rownorm_kernel(float* __restrict__ Arows, int ncols) {
  float* r = Arows + (size_t)blockIdx.x * ncols;
  int tid = threadIdx.x;
  float ss = 0.f;
  for (int d = tid; d < ncols; d += 256) { float v = r[d]; ss = fmaf(v, v, ss); }
  __shared__ float red[256];
  red[tid] = ss;
  __syncthreads();
  for (int s = 128; s > 0; s >>= 1) { if (tid < s) red[tid] += red[tid + s]; __syncthreads(); }
  float denom = sqrtf(red[0]) + 1e-12f;
  for (int d = tid; d < ncols; d += 256) r[d] = r[d] / denom;
}

// --------------------- MFMA bf16-split-3 GEMM (pool U) ----------------------
__device__ __forceinline__ uint32_t f2bf_rne(float x) {
  uint32_t u = __float_as_uint(x);
  return (u + 0x7fffu + ((u >> 16) & 1u)) >> 16;
}

__global__ __launch_bounds__(512) void gemm_mfma_kernel(const float* __restrict__ A,
                                                        const float* __restrict__ Z,
                                                        const float* __restrict__ meanp,
                                                        float* __restrict__ C) {
  constexpr int BK = 32;
  __shared__ ushort Ah[128][40], Al[128][40], Bh[128][40], Bl[128][40];
  const int tid = threadIdx.x;
  const int lane = tid & 63;
  const int w = tid >> 6;              // wave 0..7
  const int wr = w >> 2;               // 0..1 (64 rows each)
  const int wc = w & 3;                // 0..3 (32 cols each)
  const int m0 = blockIdx.y * 128;
  const int n0 = blockIdx.x * 128;

  f32x4v acc[4][2];
#pragma unroll
  for (int mi = 0; mi < 4; ++mi)
#pragma unroll
    for (int ni = 0; ni < 2; ++ni) acc[mi][ni] = (f32x4v){0.f, 0.f, 0.f, 0.f};

  float4 ra[2], rb[2];
  auto ld = [&](int s) {
    const int k0 = s * BK;
#pragma unroll
    for (int q = 0; q < 2; ++q) {
      int f4 = tid + q * 512;          // 0..1023
      int r = f4 >> 3;                 // 0..127
      int kq = (f4 & 7) * 4;
      ra[q] = *(const float4*)(A + (size_t)(m0 + r) * D_ + k0 + kq);
      float4 z = *(const float4*)(Z + (size_t)(n0 + r) * D_ + k0 + kq);
      float4 mu = *(const float4*)(meanp + k0 + kq);
      rb[q] = make_float4(z.x - mu.x, z.y - mu.y, z.z - mu.z, z.w - mu.w);
    }
  };
  auto st = [&]() {
#pragma unroll
    for (int q = 0; q < 2; ++q) {
      int f4 = tid + q * 512;
      int r = f4 >> 3;
      int kq = (f4 & 7) * 4;
      float av[4] = {ra[q].x, ra[q].y, ra[q].z, ra[q].w};
      float bv[4] = {rb[q].x, rb[q].y, rb[q].z, rb[q].w};
      ushort ah[4], al[4], bh[4], bl[4];
#pragma unroll
      for (int c = 0; c < 4; ++c) {
        uint32_t h = f2bf_rne(av[c]);
        ah[c] = (ushort)h;
        al[c] = (ushort)f2bf_rne(av[c] - __uint_as_float(h << 16));
        uint32_t g = f2bf_rne(bv[c]);
        bh[c] = (ushort)g;
        bl[c] = (ushort)f2bf_rne(bv[c] - __uint_as_float(g << 16));
      }
      *(ushort4*)&Ah[r][kq] = make_ushort4(ah[0], ah[1], ah[2], ah[3]);
      *(ushort4*)&Al[r][kq] = make_ushort4(al[0], al[1], al[2], al[3]);
      *(ushort4*)&Bh[r][kq] = make_ushort4(bh[0], bh[1], bh[2], bh[3]);
      *(ushort4*)&Bl[r][kq] = make_ushort4(bl[0], bl[1], bl[2], bl[3]);
    }
  };
  auto compute = [&]() {
    const int rl = lane & 15;
    const int koff = (lane >> 4) * 8;
    short8v a_h[4], a_l[4], b_h[2], b_l[2];
#pragma unroll
    for (int mi = 0; mi < 4; ++mi) {
      int arow = wr * 64 + mi * 16 + rl;
      a_h[mi] = *(const short8v*)&Ah[arow][koff];
      a_l[mi] = *(const short8v*)&Al[arow][koff];
    }
#pragma unroll
    for (int ni = 0; ni < 2; ++ni) {
      int brow = wc * 32 + ni * 16 + rl;
      b_h[ni] = *(const short8v*)&Bh[brow][koff];
      b_l[ni] = *(const short8v*)&Bl[brow][koff];
    }
#pragma unroll
    for (int mi = 0; mi < 4; ++mi)
#pragma unroll
      for (int ni = 0; ni < 2; ++ni) {
        acc[mi][ni] = __builtin_amdgcn_mfma_f32_16x16x32_bf16(a_h[mi], b_h[ni], acc[mi][ni], 0, 0, 0);
        acc[mi][ni] = __builtin_amdgcn_mfma_f32_16x16x32_bf16(a_h[mi], b_l[ni], acc[mi][ni], 0, 0, 0);
        acc[mi][ni] = __builtin_amdgcn_mfma_f32_16x16x32_bf16(a_l[mi], b_h[ni], acc[mi][ni], 0, 0, 0);
      }
  };

  const int nst = D_ / BK;             // 32
  ld(0);
  for (int s = 0; s < nst; ++s) {
    if (s) __syncthreads();
    st();
    __syncthreads();
    if (s + 1 < nst) ld(s + 1);
    compute();
  }

  const int rl = lane & 15;
  const int rq = (lane >> 4) * 4;
#pragma unroll
  for (int mi = 0; mi < 4; ++mi)
#pragma unroll
    for (int ni = 0; ni < 2; ++ni) {
      int col = n0 + wc * 32 + ni * 16 + rl;
#pragma unroll
      for (int r = 0; r < 4; ++r) {
        int row = m0 + wr * 64 + mi * 16 + rq + r;
        C[(size_t)row * B_ + col] = acc[mi][ni][r];
      }
    }
}

// ------------------------------- vector GEMM --------------------------------
template <int BM, int BN, int BK, int TM, int TN, int NT, bool CENTER_B>
__global__ __launch_bounds__(NT) void gemm_nt_kernel(const float* __restrict__ A,
                                                     const float* __restrict__ Bm,
                                                     const float* __restrict__ meanp,
                                                     float* __restrict__ C,
                                                     int M, int N, int K,
                                                     int lda, int ldb, int ldc) {
  static_assert(TN == 4 || TN == 8, "");
  static_assert((BM * BK) % (4 * NT) == 0, "");
  __shared__ float As[2][BK][BM + 4];
  __shared__ float Bs[2][BK][BN + 4];
  const int tid = threadIdx.x;
  constexpr int TX = BN / TN;
  constexpr int TY = NT / TX;
  static_assert(TY * TM == BM, "");
  const int tx = tid % TX;
  const int ty = tid / TX;
  const int m0 = blockIdx.y * BM;
  const int n0 = blockIdx.x * BN;
  constexpr int NF4 = (BM * BK) / (4 * NT);
  constexpr int F4R = BK / 4;

  float acc[TM][TN];
#pragma unroll
  for (int i = 0; i < TM; ++i)
#pragma unroll
    for (int j = 0; j < TN; ++j) acc[i][j] = 0.f;

  float4 ra[NF4], rb[NF4];

  auto ldnext = [&](int k0) {
#pragma unroll
    for (int q = 0; q < NF4; ++q) {
      int idx = tid + q * NT;
      int r = idx / F4R;
      int kk = (idx % F4R) * 4;
      ra[q] = *(const float4*)(A + (size_t)(m0 + r) * lda + k0 + kk);
      float4 b = *(const float4*)(Bm + (size_t)(n0 + r) * ldb + k0 + kk);
      if constexpr (CENTER_B) {
        float4 mu = *(const float4*)(meanp + k0 + kk);
        b = make_float4(b.x - mu.x, b.y - mu.y, b.z - mu.z, b.w - mu.w);
      }
      rb[q] = b;
    }
  };
  auto stnext = [&](int buf) {
#pragma unroll
    for (int q = 0; q < NF4; ++q) {
      int idx = tid + q * NT;
      int r = idx / F4R;
      int kk = (idx % F4R) * 4;
      As[buf][kk + 0][r] = ra[q].x; As[buf][kk + 1][r] = ra[q].y;
      As[buf][kk + 2][r] = ra[q].z; As[buf][kk + 3][r] = ra[q].w;
      Bs[buf][kk + 0][r] = rb[q].x; Bs[buf][kk + 1][r] = rb[q].y;
      Bs[buf][kk + 2][r] = rb[q].z; Bs[buf][kk + 3][r] = rb[q].w;
    }
  };
  auto compute = [&](int buf) {
#pragma unroll
    for (int kk = 0; kk < BK; ++kk) {
      float a[TM], b[TN];
#pragma unroll
      for (int q = 0; q < TM / 4; ++q) {
        float4 v = *(const float4*)&As[buf][kk][ty * TM + q * 4];
        a[q * 4 + 0] = v.x; a[q * 4 + 1] = v.y; a[q * 4 + 2] = v.z; a[q * 4 + 3] = v.w;
      }
      {
        float4 v = *(const float4*)&Bs[buf][kk][tx * 4];
        b[0] = v.x; b[1] = v.y; b[2] = v.z; b[3] = v.w;
      }
      if constexpr (TN == 8) {
        float4 v = *(const float4*)&Bs[buf][kk][BN / 2 + tx * 4];
        b[4] = v.x; b[5] = v.y; b[6] = v.z; b[7] = v.w;
      }
#pragma unroll
      for (int i = 0; i < TM; ++i)
#pragma unroll
        for (int j = 0; j < TN; ++j) acc[i][j] = fmaf(a[i], b[j], acc[i][j]);
    }
  };

  ldnext(0);
  stnext(0);
  __syncthreads();
  const int nst = K / BK;
  for (int s = 0; s < nst; ++s) {
    const int cur = s & 1;
    if (s + 1 < nst) ldnext((s + 1) * BK);
    compute(cur);
    if (s + 1 < nst) stnext(cur ^ 1);
    __syncthreads();
  }

#pragma unroll
  for (int i = 0; i < TM; ++i) {
    const int gm = m0 + ty * TM + i;
    float4 c0 = make_float4(acc[i][0], acc[i][1], acc[i][2], acc[i][3]);
    *(float4*)(C + (size_t)gm * ldc + n0 + tx * 4) = c0;
    if constexpr (TN == 8) {
      float4 c1 = make_float4(acc[i][4], acc[i][5], acc[i][6], acc[i][7]);
      *(float4*)(C + (size_t)gm * ldc + n0 + BN / 2 + tx * 4) = c1;
    }
  }
}

// ----------------------------- tiled gram ----------------------------------
__global__ __launch_bounds__(256) void gram_kernel(const float* __restrict__ A,
                                                   const float* __restrict__ Bm,
                                                   float* __restrict__ C,
                                                   int K, int ldc) {
  __shared__ float As[32][136];
  __shared__ float BsT[128][36];
  const int tid = threadIdx.x;
  const int i0 = blockIdx.y * 32;
  const int j0 = blockIdx.x * 32;
  const int i = tid >> 3;
  const int jl = (tid & 7) * 4;

  float s[4][4];
#pragma unroll
  for (int m = 0; m < 4; ++m)
#pragma unroll
    for (int c = 0; c < 4; ++c) s[m][c] = 0.f;

  for (int kc = 0; kc < K; kc += 128) {
#pragma unroll
    for (int q = 0; q < 4; ++q) {
      int f4 = tid + 256 * q;
      int r = f4 >> 5;
      int kq = (f4 & 31) * 4;
      float4 va = *(const float4*)(A + (size_t)(i0 + r) * K + kc + kq);
      *(float4*)&As[r][kq] = va;
      float4 vb = *(const float4*)(Bm + (size_t)(j0 + r) * K + kc + kq);
      BsT[kq + 0][r] = vb.x; BsT[kq + 1][r] = vb.y;
      BsT[kq + 2][r] = vb.z; BsT[kq + 3][r] = vb.w;
    }
    __syncthreads();
    for (int k4 = 0; k4 < 128; k4 += 4) {
#pragma unroll
      for (int c = 0; c < 4; ++c) {
        int k = k4 + c;
        float a = As[i][k];
        float4 b = *(const float4*)&BsT[k][jl];
        s[0][c] = fmaf(a, b.x, s[0][c]);
        s[1][c] = fmaf(a, b.y, s[1][c]);
        s[2][c] = fmaf(a, b.z, s[2][c]);
        s[3][c] = fmaf(a, b.w, s[3][c]);
      }
    }
    __syncthreads();
  }
#pragma unroll
  for (int m = 0; m < 4; ++m)
    C[(size_t)(i0 + i) * ldc + j0 + jl + m] = (s[m][0] + s[m][1]) + (s[m][2] + s[m][3]);
}

// --------------------------- ECF + loss ------------------------------------
__global__ __launch_bounds__(256) void ecf_loss_kernel(const float* __restrict__ U,
                                                       float* __restrict__ out_loss) {
  const float* u = U + (size_t)blockIdx.x * B_;
  const int tid = threadIdx.x;
  float sc[TS_], ss[TS_];
#pragma unroll
  for (int k = 0; k < TS_; ++k) { sc[k] = 0.f; ss[k] = 0.f; }

  for (int b = tid; b < B_; b += 256) {
    float x = u[b];
#pragma unroll
    for (int k = 0; k < TS_; ++k) {
      const double tk = -5.0 + 0.625 * (double)k;
      const float trev = (float)(tk * 0.15915494309189535);  // t_k / (2*pi)
      float r = x * trev;
      sc[k] += __builtin_amdgcn_cosf(r);
      ss[k] += __builtin_amdgcn_sinf(r);
    }
  }
#pragma unroll
  for (int k = 0; k < TS_; ++k) {
#pragma unroll
    for (int off = 32; off > 0; off >>= 1) {
      sc[k] += __shfl_down(sc[k], off, 64);
      ss[k] += __shfl_down(ss[k], off, 64);
    }
  }
  __shared__ float rsc[4][TS_], rss[4][TS_];
  int wid = tid >> 6, lane = tid & 63;
  if (lane == 0) {
#pragma unroll
    for (int k = 0; k < TS_; ++k) { rsc[wid][k] = sc[k]; rss[wid][k] = ss[k]; }
  }
  __syncthreads();
  if (tid == 0) {
    float loss = 0.f, prevI = 0.f;
#pragma unroll
    for (int k = 0; k < TS_; ++k) {
      float tk = -5.0f + 0.625f * (float)k;
      float phik = expf(-0.5f * tk * tk);
      float S = (rsc[0][k] + rsc[1][k]) + (rsc[2][k] + rsc[3][k]);
      float T = (rss[0][k] + rss[1][k]) + (rss[2][k] + rss[3][k]);
      float re = S * (1.0f / (float)B_) - phik;
      float im = T * (1.0f / (float)B_);
      float I = (re * re + im * im) * phik;
      if (k > 0) loss += 0.5f * (I + prevI) * 0.625f;
      prevI = I;
    }
    out_loss[blockIdx.x] = loss;
  }
}

// --------------------------- top-k selection -------------------------------
__global__ __launch_bounds__(1024) void sort_kernel(const float* __restrict__ loss,
                                                    int* __restrict__ ranked) {
  __shared__ float ls[P_];
  __shared__ int li[P_];
  int tid = threadIdx.x;
  for (int i = tid; i < P_; i += 1024) { ls[i] = loss[i]; li[i] = i; }
  __syncthreads();
  for (int k = 2; k <= P_; k <<= 1) {
    for (int j = k >> 1; j > 0; j >>= 1) {
      for (int i = tid; i < P_; i += 1024) {
        int ixj = i ^ j;
        if (ixj > i) {
          bool up = ((i & k) == 0);
          float la = ls[i], lb = ls[ixj];
          int ia = li[i], ib = li[ixj];
          bool a_after_b = (la < lb) || (la == lb && ia > ib);
          bool sw = up ? a_after_b : (!a_after_b && !(la == lb && ia == ib));
          if (sw) { ls[i] = lb; ls[ixj] = la; li[i] = ib; li[ixj] = ia; }
        }
      }
      __syncthreads();
    }
  }
  for (int i = tid; i < P_; i += 1024) ranked[i] = li[i];
}

__global__ __launch_bounds__(256) void gather_ht_kernel(const float* __restrict__ AT,
                                                        const int* __restrict__ ranked,
                                                        float* __restrict__ HT) {
  int j = blockIdx.x;
  int src = ranked[j];
  for (int d = threadIdx.x; d < D_; d += 256)
    HT[(size_t)j * D_ + d] = AT[(size_t)src * D_ + d];
}

// ------------------- Cholesky of G + triangular inverse --------------------
// R10: LDS-vectorized. g/w rows stride 132 (16B-aligned), m stride 116.
// Phase 1d: thread = (column-quad, row-offset); rkb preloaded as float4;
//   float4 RMW on g. Sub-diagonal overrun writes land in the never-read
//   lower triangle (verified: all later reads are upper-triangle).
// Phase 2c: float4 reads of w/m (ds_read_b128), 4 outputs per thread.
// Per-element fmaf order identical to R8 -> bit-identical W.
__global__ __launch_bounds__(512) void chol_inv_kernel(const float* __restrict__ G,
                                                       float* __restrict__ W) {
  __shared__ float g[HARD_][132];
  __shared__ float w[HARD_][132];
  __shared__ float m[16][116];
  __shared__ float rinv[HARD_];
  const int tid = threadIdx.x;

  for (int idx = tid; idx < HARD_ * HARD_; idx += 512)
    g[idx >> 7][idx & 127] = G[idx];
  for (int idx = tid; idx < HARD_ * 132; idx += 512)
    (&w[0][0])[idx] = 0.f;
  __syncthreads();

  // ---- Phase 1: blocked Cholesky (NB=16, 8 panels) ----
  const int cq = (tid & 31) << 2;        // column-quad base: 0,4,...,124
  const int roff = tid >> 5;             // 0..15
  for (int K = 0; K < 8; ++K) {
    const int b = K << 4;
    const int c0 = b + 16;
    const int nc = HARD_ - c0;

    // -- 1a: diag block factor (lanes 0..15 of wave 0, shfl-based) --
    if (tid < 16) {
      const int j = tid;
      float c[16];
#pragma unroll
      for (int k = 0; k < 16; ++k) c[k] = g[b + k][b + j];
#pragma unroll
      for (int i = 0; i < 16; ++i) {
        float rii = sqrtf(__shfl(c[i], i, 16));
        float rinvi = 1.0f / rii;
        float rij = c[i] * rinvi;
        if (j > i) c[i] = rij;
        if (j == i) c[i] = rii;
#pragma unroll
        for (int a = i + 1; a < 16; ++a) {
          float ria = __shfl(c[i], a, 16);
          if (j >= a) c[a] = fmaf(-ria, rij, c[a]);
        }
      }
#pragma unroll
      for (int k = 0; k < 16; ++k) if (k <= j) g[b + k][b + j] = c[k];
      rinv[b + j] = 1.0f / c[j];
    }
    __syncthreads();

    if (nc > 0) {
      // -- 1c: panel solve, one thread per trailing column --
      if (tid < nc) {
        const int j = c0 + tid;
        float x[16];
#pragma unroll
        for (int i = 0; i < 16; ++i) {
          float acc = g[b + i][j];
#pragma unroll
          for (int m2 = 0; m2 < i; ++m2)
            acc = fmaf(-g[b + m2][b + i], x[m2], acc);
          x[i] = acc * rinv[b + i];
        }
#pragma unroll
        for (int i = 0; i < 16; ++i) g[b + i][j] = x[i];
      }
      __syncthreads();

      // -- 1d: rank-16 trailing update, float4 column-quads --
      if (cq >= c0) {
        float4 rkb[16];
#pragma unroll
        for (int k = 0; k < 16; ++k) rkb[k] = *(const float4*)&g[b + k][cq];
        for (int a = c0 + roff; a <= cq + 3 && a < HARD_; a += 16) {
          float4 acc = *(const float4*)&g[a][cq];
#pragma unroll
          for (int k = 0; k < 16; ++k) {
            float gka = g[b + k][a];
            acc.x = fmaf(-gka, rkb[k].x, acc.x);
            acc.y = fmaf(-gka, rkb[k].y, acc.y);
            acc.z = fmaf(-gka, rkb[k].z, acc.z);
            acc.w = fmaf(-gka, rkb[k].w, acc.w);
          }
          *(float4*)&g[a][cq] = acc;
        }
      }
    }
    __syncthreads();
  }

  // ---- Phase 2b: invert 8 diagonal 16x16 blocks ----
  if (tid < HARD_) {
    const int blk = tid >> 4, j = tid & 15, b = blk << 4;
    const float myrinv = rinv[b + j];
    float wcol[16];
#pragma unroll
    for (int i = 15; i >= 0; --i) {
      float s = 0.f;
#pragma unroll
      for (int k = 15; k > i; --k) s = fmaf(g[b + i][b + k], wcol[k], s);
      float v = -rinv[b + i] * s;
      wcol[i] = (i < j) ? v : ((i == j) ? myrinv : 0.f);
    }
#pragma unroll
    for (int k = 0; k < 16; ++k) w[b + k][b + j] = wcol[k];
  }
  __syncthreads();

  // ---- Phase 2c: block-row sweep, 7 serial steps, float4 per thread ----
  for (int I = 6; I >= 0; --I) {
    const int b = I << 4;
    const int c0 = b + 16;
    const int nc = HARD_ - c0;
    const int nc4 = nc >> 2;
    const int nel4 = 16 * nc4;
    for (int e = tid; e < nel4; e += 512) {
      int r = e / nc4, c4 = (e - r * nc4) << 2;
      float4 acc = make_float4(0.f, 0.f, 0.f, 0.f);
#pragma unroll 4
      for (int k = c0; k < HARD_; ++k) {
        float gr = g[b + r][k];
        float4 wv = *(const float4*)&w[k][c0 + c4];
        acc.x = fmaf(gr, wv.x, acc.x);
        acc.y = fmaf(gr, wv.y, acc.y);
        acc.z = fmaf(gr, wv.z, acc.z);
        acc.w = fmaf(gr, wv.w, acc.w);
      }
      *(float4*)&m[r][c4] = acc;
    }
    __syncthreads();
    for (int e = tid; e < nel4; e += 512) {
      int r = e / nc4, c4 = (e - r * nc4) << 2;
      float4 acc = make_float4(0.f, 0.f, 0.f, 0.f);
#pragma unroll
      for (int rp = 0; rp < 16; ++rp) {
        float wr = w[b + r][b + rp];
        float4 mv = *(const float4*)&m[rp][c4];
        acc.x = fmaf(wr, mv.x, acc.x);
        acc.y = fmaf(wr, mv.y, acc.y);
        acc.z = fmaf(wr, mv.z, acc.z);
        acc.w = fmaf(wr, mv.w, acc.w);
      }
      *(float4*)&w[b + r][c0 + c4] =
          make_float4(-acc.x, -acc.y, -acc.z, -acc.w);
    }
    __syncthreads();
  }

  for (int idx = tid; idx < HARD_ * HARD_; idx += 512)
    W[idx] = w[idx >> 7][idx & 127];       // lower triangle zero-initialized
}

// DIRS[j][d] = sum_{i<=j} W[i][j] * HT[i][d]
__global__ __launch_bounds__(128) void apply_winv_kernel(const float* __restrict__ HT,
                                                         const float* __restrict__ W,
                                                         float* __restrict__ DIRS) {
  int j = blockIdx.y;
  int d = blockIdx.x * 128 + threadIdx.x;
  __shared__ float wc[HARD_];
  for (int i = threadIdx.x; i <= j; i += 128) wc[i] = W[i * HARD_ + j];
  __syncthreads();
  float acc = 0.f;
  for (int i = 0; i <= j; ++i) acc = fmaf(wc[i], HT[(size_t)i * D_ + d], acc);
  DIRS[(size_t)j * D_ + d] = acc;
}

__global__ __launch_bounds__(128) void proj_update_kernel(float* __restrict__ DIRS,
                                                          const float* __restrict__ C) {
  int j = blockIdx.y;
  int d = blockIdx.x * 128 + threadIdx.x;
  __shared__ float cc[HARD_];
  cc[threadIdx.x] = C[threadIdx.x * EXTRA_ + j];
  if (threadIdx.x + 128 < HARD_) cc[threadIdx.x + 128] = C[(threadIdx.x + 128) * EXTRA_ + j];
  __syncthreads();
  float acc = DIRS[(size_t)(HARD_ + j) * D_ + d];
  for (int i = 0; i < HARD_; ++i) acc = fmaf(-cc[i], DIRS[(size_t)i * D_ + d], acc);
  DIRS[(size_t)(HARD_ + j) * D_ + d] = acc;
}

__global__ __launch_bounds__(256) void finalize_kernel(const float* __restrict__ FL,
                                                       float* __restrict__ out) {
  __shared__ float red[256];
  int tid = threadIdx.x;
  red[tid] = (tid < NF_) ? FL[tid] : 0.f;
  __syncthreads();
  for (int s = 128; s > 0; s >>= 1) { if (tid < s) red[tid] += red[tid + s]; __syncthreads(); }
  if (tid == 0) out[0] = (red[0] / (float)NF_) * (float)B_;
}

// ------------------------------- host --------------------------------------

extern "C" void kernel_launch(void* const* d_in, const int* in_sizes, int n_in,
                              void* d_out, int out_size, void* d_ws, size_t ws_size,
                              hipStream_t stream) {
  const float* Z = (const float*)d_in[0];
  const int* seedp = (const int*)d_in[1];
  float* out = (float*)d_out;
  (void)in_sizes; (void)n_in; (void)out_size; (void)ws_size;

  char* ws = (char*)d_ws;
  size_t off = 0;
  auto alloc = [&](size_t bytes) -> char* {
    char* p = ws + off;
    off += (bytes + 255) & ~(size_t)255;
    return p;
  };
  float* AT   = (float*)alloc((size_t)P_ * D_ * 4);
  float* UT   = (float*)alloc((size_t)P_ * B_ * 4);
  float* LOSS = (float*)alloc(P_ * 4);
  int*   IDX  = (int*)  alloc(P_ * 4);
  float* HT   = (float*)alloc((size_t)HARD_ * D_ * 4);
  float* G    = (float*)alloc(HARD_ * HARD_ * 4);
  float* W    = (float*)alloc(HARD_ * HARD_ * 4);
  float* DIRS = (float*)alloc((size_t)NF_ * D_ * 4);
  float* PRJ  = (float*)alloc(HARD_ * EXTRA_ * 4);
  float* UF   = (float*)alloc((size_t)NF_ * B_ * 4);
  float* FL   = (float*)alloc(NF_ * 4);
  float* PART = (float*)alloc(32 * D_ * 4);
  float* MEAN = (float*)alloc(D_ * 4);

  colsum_part_kernel<<<dim3(D_ / 256, 32), 256, 0, stream>>>(Z, PART);
  colmean_fin_kernel<<<D_ / 256, 256, 0, stream>>>(PART, MEAN);

  gen_pool_norm_kernel<<<P_, 256, 0, stream>>>(AT, seedp);

  gemm_mfma_kernel<<<dim3(B_ / 128, P_ / 128), 512, 0, stream>>>(AT, Z, MEAN, UT);
  ecf_loss_kernel<<<P_, 256, 0, stream>>>(UT, LOSS);

  sort_kernel<<<1, 1024, 0, stream>>>(LOSS, IDX);
  gather_ht_kernel<<<HARD_, 256, 0, stream>>>(AT, IDX, HT);

  gram_kernel<<<dim3(HARD_ / 32, HARD_ / 32), 256, 0, stream>>>(HT, HT, G, D_, HARD_);
  chol_inv_kernel<<<1, 512, 0, stream>>>(G, W);
  apply_winv_kernel<<<dim3(D_ / 128, HARD_), 128, 0, stream>>>(HT, W, DIRS);

  gen_R_norm_kernel<<<EXTRA_, 256, 0, stream>>>(DIRS, seedp);
  gram_kernel<<<dim3(EXTRA_ / 32, HARD_ / 32), 256, 0, stream>>>(
      DIRS, DIRS + (size_t)HARD_ * D_, PRJ, D_, EXTRA_);
  proj_update_kernel<<<dim3(D_ / 128, EXTRA_), 128, 0, stream>>>(DIRS, PRJ);
  rownorm_kernel<<<EXTRA_, 256, 0, stream>>>(DIRS + (size_t)HARD_ * D_, D_);

  gemm_nt_kernel<64, 64, 32, 4, 4, 256, true><<<dim3(B_ / 64, NF_ / 64), 256, 0, stream>>>(
      DIRS, Z, MEAN, UF, NF_, B_, D_, D_, D_, B_);
  ecf_loss_kernel<<<NF_, 256, 0, stream>>>(UF, FL);
  finalize_kernel<<<1, 256, 0, stream>>>(FL, out);
}